// Round 3
// 507.191 us; speedup vs baseline: 1.0017x; 1.0017x over previous
//
#include <hip/hip_runtime.h>

// Segment sum via fixed-capacity bucketing + gather (no fp32 atomics, no scan).
// src = (1,250,000 x 64) fp32, index in [0, 50000), out = (50000 x 64) fp32.
//
// R1: atomic scatter = 1063us kernel, WRITE_SIZE 1.22 GB (atomic RMW thrash).
// R2: gather + exact counting sort = 676us, single-block scan ate ~240us.
// R3 FAILED: __shfl in a quad-divergent loop (inactive-lane bpermute = undef).
// R4: wave-uniform trip count -> 540us total (~305us is harness reset fills).
// R5: gather 2-wide load pairing, nontemporal src/bucket/out, int2 buckets.
// R6: gather 4-deep unrolled main loop (4 x 1KB wave-loads in flight, dual
//     accumulators) — attacks per-wave issue/latency limit, not bytes.
// R7: infra failure (container died twice) — no data.
// R8: fix compile error: __builtin_nontemporal_load can't take HIP int2
//     (class type); use clang ext_vector int2 for the index-pair load.

#define CAP 64
#define OVF_CAP 65536

typedef float v4f __attribute__((ext_vector_type(4)));
typedef int   v2i __attribute__((ext_vector_type(2)));

// ---- Phase 1: scatter row ids into fixed-capacity buckets (2 rows/thread) ----
__global__ __launch_bounds__(256) void bucket_kernel(
    const v2i* __restrict__ index2, int* __restrict__ count,
    int* __restrict__ bucket, int* __restrict__ ovf_n,
    int* __restrict__ ovf_rows, int n2)
{
    int i = blockIdx.x * blockDim.x + threadIdx.x;
    if (i >= n2) return;
    v2i ix = __builtin_nontemporal_load(&index2[i]);
    int row0 = i * 2, row1 = i * 2 + 1;

    int pos0 = atomicAdd(&count[ix.x], 1);
    if (pos0 < CAP) {
        __builtin_nontemporal_store(row0, &bucket[(size_t)ix.x * CAP + pos0]);
    } else {
        int o = atomicAdd(ovf_n, 1);
        if (o < OVF_CAP) ovf_rows[o] = row0;
    }
    int pos1 = atomicAdd(&count[ix.y], 1);
    if (pos1 < CAP) {
        __builtin_nontemporal_store(row1, &bucket[(size_t)ix.y * CAP + pos1]);
    } else {
        int o = atomicAdd(ovf_n, 1);
        if (o < OVF_CAP) ovf_rows[o] = row1;
    }
}

// ---- Phase 2: gather-sum, one wave per segment ----
// Lane preloads one bucket slot (coalesced 256B/wave); inner loops broadcast
// row ids via shfl with wave-uniform trip counts (ALL lanes execute the
// shfl; only loads/accumulates are predicated).
//
// Main loop is 4-deep: 4 shfls issued together, then 4 independent 1KB
// wave-loads in flight before any accumulate; two accumulators break the
// VALU dependency chain. Bounds proof for unconditional loads:
//   iters = ceil(c/4)  =>  c >= 4*iters-3.
//   Loop condition it+4 < iters  =>  it <= iters-5
//   =>  max j = 4*it+12+quad <= 4*iters-5 <= c-2 < c.   (all 16 rows valid)
// Remainder paired loop: it+1 < iters => j0 = 4*it+quad <= 4*iters-5 < c.
__global__ __launch_bounds__(256) void gather_kernel(
    const v4f* __restrict__ src4, const int* __restrict__ bucket,
    const int* __restrict__ count, v4f* __restrict__ out4, int nseg)
{
    int gid  = blockIdx.x * blockDim.x + threadIdx.x;
    int wave = gid >> 6;
    int lane = threadIdx.x & 63;
    if (wave >= nseg) return;   // wave-uniform exit

    int c = count[wave];
    if (c > CAP) c = CAP;                 // overflow handled by ovf_kernel
    int myrow = __builtin_nontemporal_load(&bucket[(size_t)wave * CAP + lane]);

    int quad = lane >> 4;                 // 4 rows per load instruction
    int col  = lane & 15;                 // float4 column within 64-col row

    v4f acc0 = {0.f, 0.f, 0.f, 0.f};
    v4f acc1 = {0.f, 0.f, 0.f, 0.f};
    int iters = (c + 3) >> 2;             // wave-uniform quad-steps
    int it = 0;

    // 4-deep main loop: 16 rows per pass, all indices provably < c.
    for (; it + 4 < iters; it += 4) {
        int j0 = (it << 2) + quad;
        int r0 = __shfl(myrow, j0,      64);
        int r1 = __shfl(myrow, j0 + 4,  64);
        int r2 = __shfl(myrow, j0 + 8,  64);
        int r3 = __shfl(myrow, j0 + 12, 64);
        v4f v0 = __builtin_nontemporal_load(&src4[(size_t)r0 * 16 + col]);
        v4f v1 = __builtin_nontemporal_load(&src4[(size_t)r1 * 16 + col]);
        v4f v2 = __builtin_nontemporal_load(&src4[(size_t)r2 * 16 + col]);
        v4f v3 = __builtin_nontemporal_load(&src4[(size_t)r3 * 16 + col]);
        acc0 += v0;
        acc1 += v1;
        acc0 += v2;
        acc1 += v3;
    }
    // paired remainder (<= 4 quad-steps left); j0 < c always holds here
    for (; it + 1 < iters; it += 2) {
        int j0 = (it << 2) + quad;
        int j1 = j0 + 4;
        int r0 = __shfl(myrow, j0, 64);
        int r1 = __shfl(myrow, j1, 64);
        v4f v0 = __builtin_nontemporal_load(&src4[(size_t)r0 * 16 + col]);
        v4f v1 = {0.f, 0.f, 0.f, 0.f};
        if (j1 < c) v1 = __builtin_nontemporal_load(&src4[(size_t)r1 * 16 + col]);
        acc0 += v0;
        acc1 += v1;
    }
    if (it < iters) {
        int j = (it << 2) + quad;
        int r = __shfl(myrow, j, 64);
        if (j < c) acc0 += __builtin_nontemporal_load(&src4[(size_t)r * 16 + col]);
    }
    acc0 += acc1;

    // reduce the 4 quad-partials (lanes ^16, ^32 share the same col)
    acc0.x += __shfl_xor(acc0.x, 16, 64);
    acc0.y += __shfl_xor(acc0.y, 16, 64);
    acc0.z += __shfl_xor(acc0.z, 16, 64);
    acc0.w += __shfl_xor(acc0.w, 16, 64);
    acc0.x += __shfl_xor(acc0.x, 32, 64);
    acc0.y += __shfl_xor(acc0.y, 32, 64);
    acc0.z += __shfl_xor(acc0.z, 32, 64);
    acc0.w += __shfl_xor(acc0.w, 32, 64);

    if (quad == 0)
        __builtin_nontemporal_store(acc0, &out4[(size_t)wave * 16 + col]);
}

// ---- Phase 3: rare overflow rows -> atomic scatter (after gather) ----
__global__ __launch_bounds__(256) void ovf_kernel(
    const v4f* __restrict__ src4, const int* __restrict__ index,
    const int* __restrict__ ovf_n, const int* __restrict__ ovf_rows,
    float* __restrict__ out)
{
    int n = *ovf_n;
    if (n > OVF_CAP) n = OVF_CAP;
    int g16    = (blockIdx.x * blockDim.x + threadIdx.x) >> 4;
    int col    = threadIdx.x & 15;
    int stride = (gridDim.x * blockDim.x) >> 4;
    for (int i = g16; i < n; i += stride) {
        int row = ovf_rows[i];
        int seg = index[row];
        v4f v = src4[(size_t)row * 16 + col];
        float* dst = out + (size_t)seg * 64 + col * 4;
        atomicAdd(dst + 0, v.x);
        atomicAdd(dst + 1, v.y);
        atomicAdd(dst + 2, v.z);
        atomicAdd(dst + 3, v.w);
    }
}

// ---- Fallback: plain atomic scatter (if ws too small) ----
__global__ __launch_bounds__(256) void scatter_add_kernel(
    const float4* __restrict__ src4, const int* __restrict__ index,
    float* __restrict__ out, int n_vec4)
{
    int gid = blockIdx.x * blockDim.x + threadIdx.x;
    if (gid >= n_vec4) return;
    int row = gid >> 4, quad = gid & 15;
    int seg = index[row];
    float4 v = src4[gid];
    float* dst = out + (size_t)seg * 64 + quad * 4;
    atomicAdd(dst + 0, v.x);
    atomicAdd(dst + 1, v.y);
    atomicAdd(dst + 2, v.z);
    atomicAdd(dst + 3, v.w);
}

extern "C" void kernel_launch(void* const* d_in, const int* in_sizes, int n_in,
                              void* d_out, int out_size, void* d_ws, size_t ws_size,
                              hipStream_t stream) {
    const float* src   = (const float*)d_in[0];
    const int*   index = (const int*)d_in[1];
    float*       out   = (float*)d_out;

    const int n_rows = in_sizes[0] / 64;   // 1,250,000
    const int nseg   = out_size / 64;      // 50,000

    // Workspace: [count nseg][ovf_n 1][ovf_rows OVF_CAP][bucket nseg*CAP]
    auto align256 = [](size_t x) { return (x + 255) & ~(size_t)255; };
    size_t off_count  = 0;
    size_t off_ovfr   = align256(off_count + (size_t)(nseg + 1) * 4);
    size_t off_bucket = align256(off_ovfr + (size_t)OVF_CAP * 4);
    size_t need       = off_bucket + (size_t)nseg * CAP * 4;

    if (ws_size < need || (n_rows & 1)) {
        (void)hipMemsetAsync(d_out, 0, (size_t)out_size * sizeof(float), stream);
        int n_vec4 = n_rows * 16;
        scatter_add_kernel<<<(n_vec4 + 255) / 256, 256, 0, stream>>>(
            (const float4*)src, index, out, n_vec4);
        return;
    }

    char* ws = (char*)d_ws;
    int* count    = (int*)(ws + off_count);
    int* ovf_n    = count + nseg;          // contiguous with count (one memset)
    int* ovf_rows = (int*)(ws + off_ovfr);
    int* bucket   = (int*)(ws + off_bucket);

    (void)hipMemsetAsync(count, 0, (size_t)(nseg + 1) * 4, stream);

    int n2 = n_rows / 2;
    bucket_kernel<<<(n2 + 255) / 256, 256, 0, stream>>>(
        (const v2i*)index, count, bucket, ovf_n, ovf_rows, n2);

    int n_threads = nseg * 64;             // one wave per segment
    gather_kernel<<<(n_threads + 255) / 256, 256, 0, stream>>>(
        (const v4f*)src, bucket, count, (v4f*)out, nseg);

    ovf_kernel<<<8, 256, 0, stream>>>(
        (const v4f*)src, index, ovf_n, ovf_rows, out);
}

// Round 4
// 498.228 us; speedup vs baseline: 1.0198x; 1.0180x over previous
//
#include <hip/hip_runtime.h>

// Segment sum via fixed-capacity bucketing + gather (no fp32 atomics, no scan).
// src = (1,250,000 x 64) fp32, index in [0, 50000), out = (50000 x 64) fp32.
//
// R1: atomic scatter = 1063us kernel, WRITE_SIZE 1.22 GB (atomic RMW thrash).
// R2: gather + exact counting sort = 676us, single-block scan ate ~240us.
// R3 FAILED: __shfl in a quad-divergent loop (inactive-lane bpermute = undef).
// R4: wave-uniform trip count -> 540us total (~305us is harness reset fills).
// R5: gather 2-wide load pairing, nontemporal src/bucket/out, int2 buckets.
// R6-R8: gather 4-deep unroll = NEUTRAL (507.2 vs 508.1). Gather is NOT
//     MLP/latency-bound -> DRAM random-256B efficiency floor. Occupancy TLP
//     already covers load latency.
// R9: bucket 4-wide (int4 index, 4 independent atomics issued before any
//     dependent store, half the threads) — tests whether phase 1 is
//     atomic-LATENCY-bound. Neutral result => all kernels at structural
//     floor => roofline.

#define CAP 64
#define OVF_CAP 65536

typedef float v4f __attribute__((ext_vector_type(4)));
typedef int   v4i __attribute__((ext_vector_type(4)));

// ---- Phase 1: scatter row ids into fixed-capacity buckets (4 rows/thread) ----
// All four atomicAdds are independent; issuing them before the dependent
// bucket stores gives 4 fabric round-trips in flight per thread (vs 2).
__global__ __launch_bounds__(256) void bucket_kernel(
    const v4i* __restrict__ index4, int* __restrict__ count,
    int* __restrict__ bucket, int* __restrict__ ovf_n,
    int* __restrict__ ovf_rows, int n4)
{
    int i = blockIdx.x * blockDim.x + threadIdx.x;
    if (i >= n4) return;
    v4i ix = __builtin_nontemporal_load(&index4[i]);
    int row0 = i * 4;

    int pos0 = atomicAdd(&count[ix.x], 1);
    int pos1 = atomicAdd(&count[ix.y], 1);
    int pos2 = atomicAdd(&count[ix.z], 1);
    int pos3 = atomicAdd(&count[ix.w], 1);

    if (pos0 < CAP) {
        __builtin_nontemporal_store(row0, &bucket[(size_t)ix.x * CAP + pos0]);
    } else {
        int o = atomicAdd(ovf_n, 1);
        if (o < OVF_CAP) ovf_rows[o] = row0;
    }
    if (pos1 < CAP) {
        __builtin_nontemporal_store(row0 + 1, &bucket[(size_t)ix.y * CAP + pos1]);
    } else {
        int o = atomicAdd(ovf_n, 1);
        if (o < OVF_CAP) ovf_rows[o] = row0 + 1;
    }
    if (pos2 < CAP) {
        __builtin_nontemporal_store(row0 + 2, &bucket[(size_t)ix.z * CAP + pos2]);
    } else {
        int o = atomicAdd(ovf_n, 1);
        if (o < OVF_CAP) ovf_rows[o] = row0 + 2;
    }
    if (pos3 < CAP) {
        __builtin_nontemporal_store(row0 + 3, &bucket[(size_t)ix.w * CAP + pos3]);
    } else {
        int o = atomicAdd(ovf_n, 1);
        if (o < OVF_CAP) ovf_rows[o] = row0 + 3;
    }
}

// ---- Phase 2: gather-sum, one wave per segment ----
// Lane preloads one bucket slot (coalesced 256B/wave); inner loops broadcast
// row ids via shfl with wave-uniform trip counts (ALL lanes execute the
// shfl; only loads/accumulates are predicated).
//
// Main loop is 4-deep: 4 shfls issued together, then 4 independent 1KB
// wave-loads in flight before any accumulate; two accumulators break the
// VALU dependency chain. Bounds proof for unconditional loads:
//   iters = ceil(c/4)  =>  c >= 4*iters-3.
//   Loop condition it+4 < iters  =>  it <= iters-5
//   =>  max j = 4*it+12+quad <= 4*iters-5 <= c-2 < c.   (all 16 rows valid)
// Remainder paired loop: it+1 < iters => j0 = 4*it+quad <= 4*iters-5 < c.
__global__ __launch_bounds__(256) void gather_kernel(
    const v4f* __restrict__ src4, const int* __restrict__ bucket,
    const int* __restrict__ count, v4f* __restrict__ out4, int nseg)
{
    int gid  = blockIdx.x * blockDim.x + threadIdx.x;
    int wave = gid >> 6;
    int lane = threadIdx.x & 63;
    if (wave >= nseg) return;   // wave-uniform exit

    int c = count[wave];
    if (c > CAP) c = CAP;                 // overflow handled by ovf_kernel
    int myrow = __builtin_nontemporal_load(&bucket[(size_t)wave * CAP + lane]);

    int quad = lane >> 4;                 // 4 rows per load instruction
    int col  = lane & 15;                 // float4 column within 64-col row

    v4f acc0 = {0.f, 0.f, 0.f, 0.f};
    v4f acc1 = {0.f, 0.f, 0.f, 0.f};
    int iters = (c + 3) >> 2;             // wave-uniform quad-steps
    int it = 0;

    // 4-deep main loop: 16 rows per pass, all indices provably < c.
    for (; it + 4 < iters; it += 4) {
        int j0 = (it << 2) + quad;
        int r0 = __shfl(myrow, j0,      64);
        int r1 = __shfl(myrow, j0 + 4,  64);
        int r2 = __shfl(myrow, j0 + 8,  64);
        int r3 = __shfl(myrow, j0 + 12, 64);
        v4f v0 = __builtin_nontemporal_load(&src4[(size_t)r0 * 16 + col]);
        v4f v1 = __builtin_nontemporal_load(&src4[(size_t)r1 * 16 + col]);
        v4f v2 = __builtin_nontemporal_load(&src4[(size_t)r2 * 16 + col]);
        v4f v3 = __builtin_nontemporal_load(&src4[(size_t)r3 * 16 + col]);
        acc0 += v0;
        acc1 += v1;
        acc0 += v2;
        acc1 += v3;
    }
    // paired remainder (<= 4 quad-steps left); j0 < c always holds here
    for (; it + 1 < iters; it += 2) {
        int j0 = (it << 2) + quad;
        int j1 = j0 + 4;
        int r0 = __shfl(myrow, j0, 64);
        int r1 = __shfl(myrow, j1, 64);
        v4f v0 = __builtin_nontemporal_load(&src4[(size_t)r0 * 16 + col]);
        v4f v1 = {0.f, 0.f, 0.f, 0.f};
        if (j1 < c) v1 = __builtin_nontemporal_load(&src4[(size_t)r1 * 16 + col]);
        acc0 += v0;
        acc1 += v1;
    }
    if (it < iters) {
        int j = (it << 2) + quad;
        int r = __shfl(myrow, j, 64);
        if (j < c) acc0 += __builtin_nontemporal_load(&src4[(size_t)r * 16 + col]);
    }
    acc0 += acc1;

    // reduce the 4 quad-partials (lanes ^16, ^32 share the same col)
    acc0.x += __shfl_xor(acc0.x, 16, 64);
    acc0.y += __shfl_xor(acc0.y, 16, 64);
    acc0.z += __shfl_xor(acc0.z, 16, 64);
    acc0.w += __shfl_xor(acc0.w, 16, 64);
    acc0.x += __shfl_xor(acc0.x, 32, 64);
    acc0.y += __shfl_xor(acc0.y, 32, 64);
    acc0.z += __shfl_xor(acc0.z, 32, 64);
    acc0.w += __shfl_xor(acc0.w, 32, 64);

    if (quad == 0)
        __builtin_nontemporal_store(acc0, &out4[(size_t)wave * 16 + col]);
}

// ---- Phase 3: rare overflow rows -> atomic scatter (after gather) ----
__global__ __launch_bounds__(256) void ovf_kernel(
    const v4f* __restrict__ src4, const int* __restrict__ index,
    const int* __restrict__ ovf_n, const int* __restrict__ ovf_rows,
    float* __restrict__ out)
{
    int n = *ovf_n;
    if (n > OVF_CAP) n = OVF_CAP;
    int g16    = (blockIdx.x * blockDim.x + threadIdx.x) >> 4;
    int col    = threadIdx.x & 15;
    int stride = (gridDim.x * blockDim.x) >> 4;
    for (int i = g16; i < n; i += stride) {
        int row = ovf_rows[i];
        int seg = index[row];
        v4f v = src4[(size_t)row * 16 + col];
        float* dst = out + (size_t)seg * 64 + col * 4;
        atomicAdd(dst + 0, v.x);
        atomicAdd(dst + 1, v.y);
        atomicAdd(dst + 2, v.z);
        atomicAdd(dst + 3, v.w);
    }
}

// ---- Fallback: plain atomic scatter (if ws too small or n_rows % 4) ----
__global__ __launch_bounds__(256) void scatter_add_kernel(
    const float4* __restrict__ src4, const int* __restrict__ index,
    float* __restrict__ out, int n_vec4)
{
    int gid = blockIdx.x * blockDim.x + threadIdx.x;
    if (gid >= n_vec4) return;
    int row = gid >> 4, quad = gid & 15;
    int seg = index[row];
    float4 v = src4[gid];
    float* dst = out + (size_t)seg * 64 + quad * 4;
    atomicAdd(dst + 0, v.x);
    atomicAdd(dst + 1, v.y);
    atomicAdd(dst + 2, v.z);
    atomicAdd(dst + 3, v.w);
}

extern "C" void kernel_launch(void* const* d_in, const int* in_sizes, int n_in,
                              void* d_out, int out_size, void* d_ws, size_t ws_size,
                              hipStream_t stream) {
    const float* src   = (const float*)d_in[0];
    const int*   index = (const int*)d_in[1];
    float*       out   = (float*)d_out;

    const int n_rows = in_sizes[0] / 64;   // 1,250,000
    const int nseg   = out_size / 64;      // 50,000

    // Workspace: [count nseg][ovf_n 1][ovf_rows OVF_CAP][bucket nseg*CAP]
    auto align256 = [](size_t x) { return (x + 255) & ~(size_t)255; };
    size_t off_count  = 0;
    size_t off_ovfr   = align256(off_count + (size_t)(nseg + 1) * 4);
    size_t off_bucket = align256(off_ovfr + (size_t)OVF_CAP * 4);
    size_t need       = off_bucket + (size_t)nseg * CAP * 4;

    if (ws_size < need || (n_rows & 3)) {
        (void)hipMemsetAsync(d_out, 0, (size_t)out_size * sizeof(float), stream);
        int n_vec4 = n_rows * 16;
        scatter_add_kernel<<<(n_vec4 + 255) / 256, 256, 0, stream>>>(
            (const float4*)src, index, out, n_vec4);
        return;
    }

    char* ws = (char*)d_ws;
    int* count    = (int*)(ws + off_count);
    int* ovf_n    = count + nseg;          // contiguous with count (one memset)
    int* ovf_rows = (int*)(ws + off_ovfr);
    int* bucket   = (int*)(ws + off_bucket);

    (void)hipMemsetAsync(count, 0, (size_t)(nseg + 1) * 4, stream);

    int n4 = n_rows / 4;
    bucket_kernel<<<(n4 + 255) / 256, 256, 0, stream>>>(
        (const v4i*)index, count, bucket, ovf_n, ovf_rows, n4);

    int n_threads = nseg * 64;             // one wave per segment
    gather_kernel<<<(n_threads + 255) / 256, 256, 0, stream>>>(
        (const v4f*)src, bucket, count, (v4f*)out, nseg);

    ovf_kernel<<<8, 256, 0, stream>>>(
        (const v4f*)src, index, ovf_n, ovf_rows, out);
}